// Round 21
// baseline (215.454 us; speedup 1.0000x reference)
//
#include <hip/hip_runtime.h>
#include <hip/hip_bf16.h>
#include <stdint.h>

// B=2, S=2048, D_MODEL=768, H=12, HD=64, 7*D=5376
typedef short short8 __attribute__((ext_vector_type(8)));
typedef float f32x4 __attribute__((ext_vector_type(4)));
typedef float f32x16 __attribute__((ext_vector_type(16)));
typedef unsigned short u16x4 __attribute__((ext_vector_type(4)));
typedef unsigned uint4v __attribute__((ext_vector_type(4)));

#define MFMA16 __builtin_amdgcn_mfma_f32_16x16x32_bf16
#define MFMA32 __builtin_amdgcn_mfma_f32_32x32x16_bf16

typedef unsigned int __attribute__((address_space(1))) as1_u32;
typedef unsigned int __attribute__((address_space(3))) as3_u32;
#define GLOAD16(gsrc, ldst) \
  __builtin_amdgcn_global_load_lds((const as1_u32*)(gsrc), (as3_u32*)(ldst), 16, 0, 0)

__device__ __forceinline__ unsigned short f2bf(float f) {
  __hip_bfloat16 h = __float2bfloat16(f);
  return *(unsigned short*)&h;
}
__device__ __forceinline__ unsigned pk2(float lo, float hi) {
  return ((unsigned)f2bf(hi) << 16) | (unsigned)f2bf(lo);
}
// vdst.row1 (lanes>=32) <-> vsrc.row0 (lanes<32)
__device__ __forceinline__ void plswap(unsigned &a, unsigned &b) {
  asm volatile("v_permlane32_swap_b32 %0, %1" : "+v"(a), "+v"(b));
}

// Build PV A-fragment for s-chunk kc2 (0..1) from a 32-s-row swapped-QK acc.
__device__ __forceinline__ short8 pv_frag(const f32x16* acc, int kc2) {
  int n = kc2 >> 1, c = kc2 & 1;
  int o0 = 2 * c, o1 = 2 * c + 1;
  unsigned x0 = pk2(acc[n][o0 * 4 + 0], acc[n][o0 * 4 + 1]);
  unsigned x1 = pk2(acc[n][o0 * 4 + 2], acc[n][o0 * 4 + 3]);
  unsigned y0 = pk2(acc[n][o1 * 4 + 0], acc[n][o1 * 4 + 1]);
  unsigned y1 = pk2(acc[n][o1 * 4 + 2], acc[n][o1 * 4 + 3]);
  plswap(x0, y0);
  plswap(x1, y1);
  uint4v fu; fu.x = x0; fu.y = x1; fu.z = y0; fu.w = y1;
  return __builtin_bit_cast(short8, fu);
}

// XCD-locality decode for (32 tt x 24 bh) grids launched as 768 1-D blocks:
// blocks with the same bh-group land on the same XCD (linear%8 round-robin).
__device__ __forceinline__ void xcd_decode(int L, int& tt, int& bh) {
  int inner = L >> 3;
  tt = inner & 31;
  bh = (L & 7) * 3 + (inner >> 5);
}

// ---------------- fused convert f32 -> bf16 for all three weight/input buffers ------
__global__ __launch_bounds__(256) void cvt_all(const float* __restrict__ a,
                                               unsigned short* __restrict__ ao, int na,
                                               const float* __restrict__ bsrc,
                                               unsigned short* __restrict__ bo, int nb,
                                               const float* __restrict__ csrc,
                                               unsigned short* __restrict__ co, int nc) {
  int e = (blockIdx.x * 256 + threadIdx.x) * 4;
  const float* src;
  unsigned short* dst;
  if (e < na) { src = a + e; dst = ao + e; }
  else if (e < na + nb) { src = bsrc + (e - na); dst = bo + (e - na); }
  else if (e < na + nb + nc) { src = csrc + (e - na - nb); dst = co + (e - na - nb); }
  else return;
  f32x4 v = *(const f32x4*)src;
  u16x4 o;
  o.x = f2bf(v.x); o.y = f2bf(v.y); o.z = f2bf(v.z); o.w = f2bf(v.w);
  *(u16x4*)dst = o;
}

// ---------------- 64x64 head-tile transpose: src[b][s][stride] -> dst[bh][d][2048] ----
__global__ __launch_bounds__(256) void transp64(const unsigned short* __restrict__ src,
                                                int stride, int off,
                                                unsigned short* __restrict__ dst) {
  __shared__ __align__(16) unsigned short t[64 * 64];
  const int tid = threadIdx.x;
  const int tt = blockIdx.x, bh = blockIdx.y;
  const int b = bh / 12, h = bh % 12;
  const unsigned short* sbase = src + (size_t)(b * 2048 + tt * 64) * stride + h * 64 + off;
  for (int it = 0; it < 2; ++it) {
    int slot = it * 256 + tid, s = slot >> 3, j = slot & 7;
    short8 v = *(const short8*)(sbase + (size_t)s * stride + j * 8);
    int phys = (s + 8 * j) & 63;
    for (int e = 0; e < 8; ++e)
      t[(j * 8 + e) * 64 + phys] = ((unsigned short*)&v)[e];
  }
  __syncthreads();
  unsigned short* dbase = dst + (size_t)bh * 64 * 2048 + tt * 64;
  for (int it = 0; it < 2; ++it) {
    int slot = it * 256 + tid, d = slot >> 3, c = slot & 7;
    int pc = (c + (d >> 3)) & 7;
    short8 v = *(const short8*)(t + d * 64 + pc * 8);
    *(short8*)(dbase + (size_t)d * 2048 + c * 8) = v;
  }
}

// ---------------- GEMM: C[M][N] = A[M][K] * B[N][K]^T + bias, XCD-swizzled ----------
template <bool OUT_BF16>
__global__ __launch_bounds__(256) void gemm_nt(const unsigned short* __restrict__ A,
                                               const unsigned short* __restrict__ Bm,
                                               const float* __restrict__ bias,
                                               void* __restrict__ Cout,
                                               int M, int N, int K) {
  __shared__ __align__(16) char smem[32768];
  char* As = smem;
  char* Bs = smem + 16384;
  const int tid = threadIdx.x;
  const int w = tid >> 6, l = tid & 63;
  const int wm = w >> 1, wn = w & 1;
  const int gx = gridDim.x;
  const int lin = blockIdx.y * gx + blockIdx.x;
  const int cpx = (gx * gridDim.y) >> 3;
  const int swz = (lin & 7) * cpx + (lin >> 3);
  const int Row0 = (swz / gx) * 128, Col0 = (swz % gx) * 128;

  f32x4 z; z.x = 0.f; z.y = 0.f; z.z = 0.f; z.w = 0.f;
  f32x4 acc[4][4];
  for (int m = 0; m < 4; ++m)
    for (int n = 0; n < 4; ++n) acc[m][n] = z;

  for (int k0 = 0; k0 < K; k0 += 64) {
    for (int it = 0; it < 4; ++it) {
      int slot = it * 256 + tid;
      int row = slot >> 3, j = slot & 7;
      int gc = j ^ (row & 7);
      GLOAD16(A + (size_t)(Row0 + row) * K + k0 + gc * 8, As + slot * 16);
      GLOAD16(Bm + (size_t)(Col0 + row) * K + k0 + gc * 8, Bs + slot * 16);
    }
    __syncthreads();
    for (int kc = 0; kc < 2; ++kc) {
      int c = (l >> 4) + 4 * kc;
      short8 af[4], bf[4];
      for (int m = 0; m < 4; ++m) {
        int t = wm * 64 + m * 16 + (l & 15);
        af[m] = *(const short8*)(As + t * 128 + ((c ^ (t & 7)) * 16));
      }
      for (int n = 0; n < 4; ++n) {
        int t = wn * 64 + n * 16 + (l & 15);
        bf[n] = *(const short8*)(Bs + t * 128 + ((c ^ (t & 7)) * 16));
      }
      for (int m = 0; m < 4; ++m)
        for (int n = 0; n < 4; ++n)
          acc[m][n] = MFMA16(af[m], bf[n], acc[m][n], 0, 0, 0);
    }
    __syncthreads();
  }
  for (int n = 0; n < 4; ++n) {
    int col = Col0 + wn * 64 + n * 16 + (l & 15);
    float bv = bias[col];
    for (int m = 0; m < 4; ++m) {
      int rbase = Row0 + wm * 64 + m * 16 + (l >> 4) * 4;
      for (int r = 0; r < 4; ++r) {
        float v = acc[m][n][r] + bv;
        size_t idx = (size_t)(rbase + r) * N + col;
        if (OUT_BF16) ((unsigned short*)Cout)[idx] = f2bf(v);
        else          ((float*)Cout)[idx] = v;
      }
    }
  }
}

// ---------------- GEMM2 with fused GroupNorm on the A operand -----------------------
// A = normalize(ctx) computed on the fly (reg-staged); B = out_w bf16; out f32.
// M=4096, N=768, K=768. Grid (6, 32) = 192 blocks (div by 8 -> XCD swizzle ok).
__global__ __launch_bounds__(256) void gemm_gn(const float* __restrict__ ctx,
                                               const float* __restrict__ stats,
                                               const float* __restrict__ gw,
                                               const float* __restrict__ gb,
                                               const unsigned short* __restrict__ Bm,
                                               const float* __restrict__ bias,
                                               float* __restrict__ Cout) {
  __shared__ __align__(16) char smem[32768];
  char* As = smem;
  char* Bs = smem + 16384;
  const int tid = threadIdx.x;
  const int w = tid >> 6, l = tid & 63;
  const int wm = w >> 1, wn = w & 1;
  const int gx = gridDim.x;
  const int lin = blockIdx.y * gx + blockIdx.x;
  const int cpx = (gx * gridDim.y) >> 3;
  const int swz = (lin & 7) * cpx + (lin >> 3);
  const int Row0 = (swz / gx) * 128, Col0 = (swz % gx) * 128;
  const int N = 768, K = 768;

  f32x4 z; z.x = 0.f; z.y = 0.f; z.z = 0.f; z.w = 0.f;
  f32x4 acc[4][4];
  for (int m = 0; m < 4; ++m)
    for (int n = 0; n < 4; ++n) acc[m][n] = z;

  for (int k0 = 0; k0 < K; k0 += 64) {
    // B tile via async LDS; A tile reg-staged with fused normalize
    for (int it = 0; it < 4; ++it) {
      int slot = it * 256 + tid;
      int row = slot >> 3, j = slot & 7;
      int gc = j ^ (row & 7);
      GLOAD16(Bm + (size_t)(Col0 + row) * K + k0 + gc * 8, Bs + slot * 16);
    }
    for (int it = 0; it < 4; ++it) {
      int slot = it * 256 + tid;
      int row = slot >> 3, j = slot & 7;
      int gc = j ^ (row & 7);
      int grow = Row0 + row;                 // global row 0..4095
      int col = k0 + gc * 8;                 // global col, 8-aligned, within one 64-grp
      int g = (grow >> 11) * 12 + (col >> 6);
      float mean = stats[2 * g], rstd = stats[2 * g + 1];
      const float* src = ctx + (size_t)grow * 768 + col;
      f32x4 v0 = *(const f32x4*)src;
      f32x4 v1 = *(const f32x4*)(src + 4);
      f32x4 w0 = *(const f32x4*)(gw + col);
      f32x4 w1 = *(const f32x4*)(gw + col + 4);
      f32x4 b0 = *(const f32x4*)(gb + col);
      f32x4 b1 = *(const f32x4*)(gb + col + 4);
      uint4v pk;
      pk.x = pk2((v0.x - mean) * rstd * w0.x + b0.x, (v0.y - mean) * rstd * w0.y + b0.y);
      pk.y = pk2((v0.z - mean) * rstd * w0.z + b0.z, (v0.w - mean) * rstd * w0.w + b0.w);
      pk.z = pk2((v1.x - mean) * rstd * w1.x + b1.x, (v1.y - mean) * rstd * w1.y + b1.y);
      pk.w = pk2((v1.z - mean) * rstd * w1.z + b1.z, (v1.w - mean) * rstd * w1.w + b1.w);
      *(uint4v*)(As + slot * 16) = pk;
    }
    __syncthreads();
    for (int kc = 0; kc < 2; ++kc) {
      int c = (l >> 4) + 4 * kc;
      short8 af[4], bf[4];
      for (int m = 0; m < 4; ++m) {
        int t = wm * 64 + m * 16 + (l & 15);
        af[m] = *(const short8*)(As + t * 128 + ((c ^ (t & 7)) * 16));
      }
      for (int n = 0; n < 4; ++n) {
        int t = wn * 64 + n * 16 + (l & 15);
        bf[n] = *(const short8*)(Bs + t * 128 + ((c ^ (t & 7)) * 16));
      }
      for (int m = 0; m < 4; ++m)
        for (int n = 0; n < 4; ++n)
          acc[m][n] = MFMA16(af[m], bf[n], acc[m][n], 0, 0, 0);
    }
    __syncthreads();
  }
  for (int n = 0; n < 4; ++n) {
    int col = Col0 + wn * 64 + n * 16 + (l & 15);
    float bv = bias[col];
    for (int m = 0; m < 4; ++m) {
      int rbase = Row0 + wm * 64 + m * 16 + (l >> 4) * 4;
      for (int r = 0; r < 4; ++r) {
        float v = acc[m][n][r] + bv;
        Cout[(size_t)(rbase + r) * N + col] = v;
      }
    }
  }
}

// ---------------- pass1: 4 waves (2 mat x 2 s-half), T=64/wave, s-tile 32, dbuf ------
// 768 1-D blocks, XCD-locality decode (same bh-group -> same XCD). Writes u^T.
__global__ __launch_bounds__(256) void pass1(const unsigned short* __restrict__ qkv,
                                             const unsigned short* __restrict__ vt,
                                             unsigned short* __restrict__ ut) {
  __shared__ __align__(16) char smem[49152];  // 2 bufs x 2 sh x (K1 4K|K2 4K|V 4K)
  const int tid = threadIdx.x, w = tid >> 6, l = tid & 63;
  const int m = w & 1, sh = w >> 1;
  const int g5 = l >> 5, l31 = l & 31;
  int tt, bh;
  xcd_decode(blockIdx.x, tt, bh);
  const int b = bh / 12, h = bh % 12;

  // Q fragments (B-operand of swapped QK): [tb][kc], t = tt*64 + tb*32 + l31
  short8 qf[2][4];
#pragma unroll
  for (int tb = 0; tb < 2; ++tb) {
    const unsigned short* qrow =
        qkv + (size_t)(b * 2048 + tt * 64 + tb * 32 + l31) * 5376 + h * 64 + m * 2 * 768;
#pragma unroll
    for (int kc = 0; kc < 4; ++kc)
      qf[tb][kc] = *(const short8*)(qrow + kc * 16 + g5 * 8);
  }

  f32x16 z16;
#pragma unroll
  for (int i = 0; i < 16; ++i) z16[i] = 0.f;
  f32x16 tacc[2][2];  // [tb][dn]
  tacc[0][0] = z16; tacc[0][1] = z16; tacc[1][0] = z16; tacc[1][1] = z16;

  // stage both halves' K1,K2,V (s-tile 32): 6 GLOAD16/thread
  auto STAGE = [&](char* buf, int si) {
#pragma unroll
    for (int shs = 0; shs < 2; ++shs) {
      int s0 = shs * 1024 + si * 32;
      char* hb = buf + shs * 12288;
      {
        int row = tid >> 3, pc = tid & 7, gc = pc ^ (row & 7);
        const unsigned short* base =
            qkv + (size_t)(b * 2048 + s0 + row) * 5376 + h * 64 + gc * 8;
        GLOAD16(base + 768, hb + tid * 16);              // K1
        GLOAD16(base + 3 * 768, hb + 4096 + tid * 16);   // K2
      }
      {
        int row = tid >> 2, pc = tid & 3, gc = pc ^ ((row >> 1) & 3);
        GLOAD16(vt + (size_t)(bh * 64 + row) * 2048 + s0 + gc * 8,
                hb + 8192 + tid * 16);                   // V^T [64d][32s]
      }
    }
  };

  STAGE(smem, 0);
  __syncthreads();
  for (int si = 0; si < 32; ++si) {
    const char* cur = smem + (si & 1) * 24576 + sh * 12288;
    if (si < 31) STAGE(smem + ((si + 1) & 1) * 24576, si + 1);
    const char* Ks = cur + m * 4096;
    const char* Vs = cur + 8192;

    short8 kreg[4], vreg[4];
#pragma unroll
    for (int kc = 0; kc < 4; ++kc)
      kreg[kc] = *(const short8*)(Ks + l31 * 128 + (((kc * 2 + g5) ^ (l31 & 7)) * 16));
#pragma unroll
    for (int kc2 = 0; kc2 < 2; ++kc2)
#pragma unroll
      for (int dn = 0; dn < 2; ++dn) {
        int drow = dn * 32 + l31, c = kc2 * 2 + g5;
        vreg[kc2 * 2 + dn] =
            *(const short8*)(Vs + drow * 64 + ((c ^ ((drow >> 1) & 3)) * 16));
      }

#pragma unroll
    for (int tb = 0; tb < 2; ++tb) {
      f32x16 a = z16;
#pragma unroll
      for (int kc = 0; kc < 4; ++kc)
        a = MFMA32(kreg[kc], qf[tb][kc], a, 0, 0, 0);
#pragma unroll
      for (int kc2 = 0; kc2 < 2; ++kc2) {
        short8 pa = pv_frag(&a, kc2);
#pragma unroll
        for (int dn = 0; dn < 2; ++dn)
          tacc[tb][dn] = MFMA32(pa, vreg[kc2 * 2 + dn], tacc[tb][dn], 0, 0, 0);
      }
    }
    __syncthreads();
  }

  // epilogue: combine s-halves (per mat), then u^T = silu(t1)*t2 by mat-0 wave
  float* ex = (float*)smem;
  if (sh == 1) {
#pragma unroll
    for (int tb = 0; tb < 2; ++tb)
#pragma unroll
      for (int dn = 0; dn < 2; ++dn)
#pragma unroll
        for (int qd = 0; qd < 4; ++qd) {
          f32x4 v;
          v.x = tacc[tb][dn][qd * 4 + 0]; v.y = tacc[tb][dn][qd * 4 + 1];
          v.z = tacc[tb][dn][qd * 4 + 2]; v.w = tacc[tb][dn][qd * 4 + 3];
          *(f32x4*)((char*)ex + m * 16384 + ((tb * 2 + dn) * 4 + qd) * 1024 + l * 16) = v;
        }
  }
  __syncthreads();
  if (sh == 0) {
#pragma unroll
    for (int tb = 0; tb < 2; ++tb)
#pragma unroll
      for (int dn = 0; dn < 2; ++dn)
#pragma unroll
        for (int qd = 0; qd < 4; ++qd) {
          f32x4 v = *(const f32x4*)((char*)ex + m * 16384 +
                                    ((tb * 2 + dn) * 4 + qd) * 1024 + l * 16);
          tacc[tb][dn][qd * 4 + 0] += v.x; tacc[tb][dn][qd * 4 + 1] += v.y;
          tacc[tb][dn][qd * 4 + 2] += v.z; tacc[tb][dn][qd * 4 + 3] += v.w;
        }
  }
  __syncthreads();
  if (sh == 0 && m == 1) {
#pragma unroll
    for (int tb = 0; tb < 2; ++tb)
#pragma unroll
      for (int dn = 0; dn < 2; ++dn)
#pragma unroll
        for (int qd = 0; qd < 4; ++qd) {
          f32x4 v;
          v.x = tacc[tb][dn][qd * 4 + 0]; v.y = tacc[tb][dn][qd * 4 + 1];
          v.z = tacc[tb][dn][qd * 4 + 2]; v.w = tacc[tb][dn][qd * 4 + 3];
          *(f32x4*)((char*)ex + ((tb * 2 + dn) * 4 + qd) * 1024 + l * 16) = v;
        }
  }
  __syncthreads();
  if (sh == 0 && m == 0) {
    // compute uu, transpose through 4KB swizzled LDS scratch, write u^T coalesced
    char* sc = smem + 32768;   // [64 d][64 t] bf16, tile-swizzled (4KB)
#pragma unroll
    for (int tb = 0; tb < 2; ++tb)
#pragma unroll
      for (int dn = 0; dn < 2; ++dn)
#pragma unroll
        for (int r = 0; r < 16; ++r) {
          float x2 = ex[((tb * 2 + dn) * 4 + (r >> 2)) * 256 + l * 4 + (r & 3)];
          int crow = (r & 3) + 8 * (r >> 2) + 4 * g5;
          int t = tb * 32 + crow;          // local t 0..63
          int d = dn * 32 + l31;
          float x1 = tacc[tb][dn][r];
          float uu = (x1 / (1.f + expf(-x1))) * x2;
          *(unsigned short*)(sc + d * 128 + (((t >> 3) ^ (d & 7)) * 16) + (t & 7) * 2) =
              f2bf(uu);
        }
    asm volatile("s_waitcnt lgkmcnt(0)" ::: "memory");
#pragma unroll
    for (int rr = 0; rr < 8; ++rr) {
      int drow = rr * 8 + (l >> 3), jc = l & 7;
      short8 v = *(const short8*)(sc + drow * 128 + ((jc ^ (drow & 7)) * 16));
      *(short8*)(ut + (size_t)(bh * 64 + drow) * 2048 + tt * 64 + jc * 8) = v;
    }
  }
}

// ---------------- pass2: 4 waves (4 s-quarters), T=64/wave, s-tile 32, dbuf ---------
// 768 1-D blocks, XCD-locality decode. 2 x 32KB buffers.
__global__ __launch_bounds__(256) void pass2(const unsigned short* __restrict__ qkv,
                                             const unsigned short* __restrict__ ut,
                                             float* __restrict__ ctx,
                                             float* __restrict__ partials) {
  __shared__ __align__(16) char smem[65536];  // 2 bufs x 4 quarters x (K3 4K | U 4K)
  const int tid = threadIdx.x, w = tid >> 6, l = tid & 63;
  const int g5 = l >> 5, l31 = l & 31;
  int tt, bh;
  xcd_decode(blockIdx.x, tt, bh);
  const int b = bh / 12, h = bh % 12;

  short8 qf[2][4];
#pragma unroll
  for (int tb = 0; tb < 2; ++tb) {
    const unsigned short* qrow =
        qkv + (size_t)(b * 2048 + tt * 64 + tb * 32 + l31) * 5376 + h * 64 + 4 * 768;
#pragma unroll
    for (int kc = 0; kc < 4; ++kc)
      qf[tb][kc] = *(const short8*)(qrow + kc * 16 + g5 * 8);
  }

  f32x16 z16;
#pragma unroll
  for (int i = 0; i < 16; ++i) z16[i] = 0.f;
  f32x16 ca[2][2];  // [tb][dn]
  ca[0][0] = z16; ca[0][1] = z16; ca[1][0] = z16; ca[1][1] = z16;

  const unsigned short *kp0, *kp1, *kp2, *kp3, *up0, *up1, *up2, *up3;
  {
    int row = tid >> 3, pc = tid & 7, gc = pc ^ (row & 7);
    kp0 = qkv + (size_t)(b * 2048 + row) * 5376 + h * 64 + 5 * 768 + gc * 8;
    kp1 = kp0 + (size_t)512 * 5376;
    kp2 = kp1 + (size_t)512 * 5376;
    kp3 = kp2 + (size_t)512 * 5376;
    int rowv = tid >> 2, pcv = tid & 3, gcv = pcv ^ ((rowv >> 1) & 3);
    up0 = ut + (size_t)(bh * 64 + rowv) * 2048 + gcv * 8;
    up1 = up0 + 512; up2 = up1 + 512; up3 = up2 + 512;
  }
  auto STAGE = [&](char* buf) {
    GLOAD16(kp0, buf + tid * 16);
    GLOAD16(up0, buf + 4096 + tid * 16);
    GLOAD16(kp1, buf + 8192 + tid * 16);
    GLOAD16(up1, buf + 12288 + tid * 16);
    GLOAD16(kp2, buf + 16384 + tid * 16);
    GLOAD16(up2, buf + 20480 + tid * 16);
    GLOAD16(kp3, buf + 24576 + tid * 16);
    GLOAD16(up3, buf + 28672 + tid * 16);
    kp0 += 32 * 5376; kp1 += 32 * 5376; kp2 += 32 * 5376; kp3 += 32 * 5376;
    up0 += 32; up1 += 32; up2 += 32; up3 += 32;
  };

  STAGE(smem);
  __syncthreads();
  for (int si = 0; si < 16; ++si) {
    const char* cur = smem + (si & 1) * 32768;
    if (si < 15) STAGE(smem + ((si + 1) & 1) * 32768);
    const char* Ks = cur + w * 8192;
    const char* Us = Ks + 4096;

    short8 kreg[4], ureg[4];
#pragma unroll
    for (int kc = 0; kc < 4; ++kc)
      kreg[kc] = *(const short8*)(Ks + l31 * 128 + (((kc * 2 + g5) ^ (l31 & 7)) * 16));
#pragma unroll
    for (int kc2 = 0; kc2 < 2; ++kc2)
#pragma unroll
      for (int dn = 0; dn < 2; ++dn) {
        int drow = dn * 32 + l31, c = kc2 * 2 + g5;
        ureg[kc2 * 2 + dn] =
            *(const short8*)(Us + drow * 64 + ((c ^ ((drow >> 1) & 3)) * 16));
      }

#pragma unroll
    for (int tb = 0; tb < 2; ++tb) {
      f32x16 a = z16;
#pragma unroll
      for (int kc = 0; kc < 4; ++kc)
        a = MFMA32(kreg[kc], qf[tb][kc], a, 0, 0, 0);
#pragma unroll
      for (int kc2 = 0; kc2 < 2; ++kc2) {
        short8 pa = pv_frag(&a, kc2);
#pragma unroll
        for (int dn = 0; dn < 2; ++dn)
          ca[tb][dn] = MFMA32(pa, ureg[kc2 * 2 + dn], ca[tb][dn], 0, 0, 0);
      }
    }
    __syncthreads();
  }

  // epilogue: tree-combine quarters -> wave 0
  float* ex = (float*)smem;
  auto DUMP = [&](int region) {
#pragma unroll
    for (int tb = 0; tb < 2; ++tb)
#pragma unroll
      for (int dn = 0; dn < 2; ++dn)
#pragma unroll
        for (int qd = 0; qd < 4; ++qd) {
          f32x4 v;
          v.x = ca[tb][dn][qd * 4 + 0]; v.y = ca[tb][dn][qd * 4 + 1];
          v.z = ca[tb][dn][qd * 4 + 2]; v.w = ca[tb][dn][qd * 4 + 3];
          *(f32x4*)((char*)ex + region * 16384 + ((tb * 2 + dn) * 4 + qd) * 1024 + l * 16) = v;
        }
  };
  auto ACCUM = [&](int region) {
#pragma unroll
    for (int tb = 0; tb < 2; ++tb)
#pragma unroll
      for (int dn = 0; dn < 2; ++dn)
#pragma unroll
        for (int qd = 0; qd < 4; ++qd) {
          f32x4 v = *(const f32x4*)((char*)ex + region * 16384 +
                                    ((tb * 2 + dn) * 4 + qd) * 1024 + l * 16);
          ca[tb][dn][qd * 4 + 0] += v.x; ca[tb][dn][qd * 4 + 1] += v.y;
          ca[tb][dn][qd * 4 + 2] += v.z; ca[tb][dn][qd * 4 + 3] += v.w;
        }
  };
  if (w == 1) DUMP(0);
  if (w == 3) DUMP(1);
  __syncthreads();
  if (w == 0) ACCUM(0);
  if (w == 2) ACCUM(1);
  __syncthreads();
  if (w == 2) DUMP(0);
  __syncthreads();
  float psum = 0.f, psum2 = 0.f;
  if (w == 0) {
    ACCUM(0);
#pragma unroll
    for (int tb = 0; tb < 2; ++tb)
#pragma unroll
      for (int dn = 0; dn < 2; ++dn)
#pragma unroll
        for (int r = 0; r < 16; ++r) {
          int t = tt * 64 + tb * 32 + (r & 3) + 8 * (r >> 2) + 4 * g5;
          int d = dn * 32 + l31;
          float v = ca[tb][dn][r];
          ctx[(size_t)(b * 2048 + t) * 768 + h * 64 + d] = v;
          psum += v; psum2 += v * v;
        }
    for (int off = 32; off > 0; off >>= 1) {
      psum += __shfl_down(psum, off, 64);
      psum2 += __shfl_down(psum2, off, 64);
    }
    if (l == 0) {
      partials[(bh * 32 + tt) * 2] = psum;
      partials[(bh * 32 + tt) * 2 + 1] = psum2;
    }
  }
}

// ---------------- finalize GN stats from 32 partials per group ----------------
__global__ __launch_bounds__(64) void gn_finalize(const float* __restrict__ partials,
                                                  float* __restrict__ stats) {
  const int g = blockIdx.x;
  const int l = threadIdx.x;
  double s = 0.0, s2 = 0.0;
  if (l < 32) {
    s = (double)partials[(g * 32 + l) * 2];
    s2 = (double)partials[(g * 32 + l) * 2 + 1];
  }
  for (int off = 32; off > 0; off >>= 1) {
    s += __shfl_down(s, off, 64);
    s2 += __shfl_down(s2, off, 64);
  }
  if (l == 0) {
    const double N = 2048.0 * 64.0;
    double mean = s / N;
    double var = s2 / N - mean * mean;
    stats[g * 2] = (float)mean;
    stats[g * 2 + 1] = (float)(1.0 / sqrt(var + 1e-5));
  }
}

extern "C" void kernel_launch(void* const* d_in, const int* in_sizes, int n_in,
                              void* d_out, int out_size, void* d_ws, size_t ws_size,
                              hipStream_t stream) {
  const float* x   = (const float*)d_in[0];
  const float* Wpw = (const float*)d_in[1];
  const float* Wpb = (const float*)d_in[2];
  const float* gnw = (const float*)d_in[3];
  const float* gnb = (const float*)d_in[4];
  const float* ow  = (const float*)d_in[5];
  const float* ob  = (const float*)d_in[6];
  float* out = (float*)d_out;

  char* ws = (char*)d_ws;
  size_t off = 0;
  auto carve = [&](size_t bytes) {
    char* p = ws + off;
    off = (off + bytes + 255) & ~(size_t)255;
    return p;
  };
  unsigned short* xb   = (unsigned short*)carve((size_t)4096 * 768 * 2);
  unsigned short* wb   = (unsigned short*)carve((size_t)5376 * 768 * 2);
  unsigned short* owb  = (unsigned short*)carve((size_t)768 * 768 * 2);
  unsigned short* qkvb = (unsigned short*)carve((size_t)4096 * 5376 * 2);
  unsigned short* vtb  = (unsigned short*)carve((size_t)24 * 64 * 2048 * 2); // V^T
  unsigned short* utb  = (unsigned short*)carve((size_t)24 * 64 * 2048 * 2); // u^T
  float* ctx           = (float*)carve((size_t)4096 * 768 * 4);
  float* partials      = (float*)carve(24 * 32 * 2 * 4);
  float* stats         = (float*)carve(48 * 4);

  const int na = 4096 * 768, nb = 5376 * 768, nc = 768 * 768;
  cvt_all<<<(na + nb + nc) / 4 / 256, 256, 0, stream>>>(x, xb, na, Wpw, wb, nb, ow, owb, nc);

  gemm_nt<true><<<dim3(42, 32), 256, 0, stream>>>(xb, wb, Wpb, qkvb, 4096, 5376, 768);
  transp64<<<dim3(32, 24), 256, 0, stream>>>(qkvb, 5376, 6 * 768, vtb);   // V -> V^T
  pass1<<<768, 256, 0, stream>>>(qkvb, vtb, utb);                         // writes u^T
  pass2<<<768, 256, 0, stream>>>(qkvb, utb, ctx, partials);
  gn_finalize<<<24, 64, 0, stream>>>(partials, stats);
  gemm_gn<<<dim3(6, 32), 256, 0, stream>>>(ctx, stats, gnw, gnb, owb, ob, out);
}

// Round 22
// 209.596 us; speedup vs baseline: 1.0279x; 1.0279x over previous
//
#include <hip/hip_runtime.h>
#include <hip/hip_bf16.h>
#include <stdint.h>

// B=2, S=2048, D_MODEL=768, H=12, HD=64, 7*D=5376
typedef short short8 __attribute__((ext_vector_type(8)));
typedef float f32x4 __attribute__((ext_vector_type(4)));
typedef float f32x16 __attribute__((ext_vector_type(16)));
typedef unsigned short u16x4 __attribute__((ext_vector_type(4)));
typedef unsigned uint4v __attribute__((ext_vector_type(4)));

#define MFMA16 __builtin_amdgcn_mfma_f32_16x16x32_bf16
#define MFMA32 __builtin_amdgcn_mfma_f32_32x32x16_bf16

typedef unsigned int __attribute__((address_space(1))) as1_u32;
typedef unsigned int __attribute__((address_space(3))) as3_u32;
#define GLOAD16(gsrc, ldst) \
  __builtin_amdgcn_global_load_lds((const as1_u32*)(gsrc), (as3_u32*)(ldst), 16, 0, 0)

__device__ __forceinline__ unsigned short f2bf(float f) {
  __hip_bfloat16 h = __float2bfloat16(f);
  return *(unsigned short*)&h;
}
__device__ __forceinline__ unsigned pk2(float lo, float hi) {
  return ((unsigned)f2bf(hi) << 16) | (unsigned)f2bf(lo);
}
// vdst.row1 (lanes>=32) <-> vsrc.row0 (lanes<32)
__device__ __forceinline__ void plswap(unsigned &a, unsigned &b) {
  asm volatile("v_permlane32_swap_b32 %0, %1" : "+v"(a), "+v"(b));
}

// Build PV A-fragment for s-chunk kc2 (0..1) from a 32-s-row swapped-QK acc.
__device__ __forceinline__ short8 pv_frag(const f32x16* acc, int kc2) {
  int n = kc2 >> 1, c = kc2 & 1;
  int o0 = 2 * c, o1 = 2 * c + 1;
  unsigned x0 = pk2(acc[n][o0 * 4 + 0], acc[n][o0 * 4 + 1]);
  unsigned x1 = pk2(acc[n][o0 * 4 + 2], acc[n][o0 * 4 + 3]);
  unsigned y0 = pk2(acc[n][o1 * 4 + 0], acc[n][o1 * 4 + 1]);
  unsigned y1 = pk2(acc[n][o1 * 4 + 2], acc[n][o1 * 4 + 3]);
  plswap(x0, y0);
  plswap(x1, y1);
  uint4v fu; fu.x = x0; fu.y = x1; fu.z = y0; fu.w = y1;
  return __builtin_bit_cast(short8, fu);
}

// XCD-locality decode for (32 tt x 24 bh) grids launched as 768 1-D blocks:
// blocks with the same bh-group land on the same XCD (linear%8 round-robin).
__device__ __forceinline__ void xcd_decode(int L, int& tt, int& bh) {
  int inner = L >> 3;
  tt = inner & 31;
  bh = (L & 7) * 3 + (inner >> 5);
}

// ---------------- fused convert f32 -> bf16 for all three weight/input buffers ------
__global__ __launch_bounds__(256) void cvt_all(const float* __restrict__ a,
                                               unsigned short* __restrict__ ao, int na,
                                               const float* __restrict__ bsrc,
                                               unsigned short* __restrict__ bo, int nb,
                                               const float* __restrict__ csrc,
                                               unsigned short* __restrict__ co, int nc) {
  int e = (blockIdx.x * 256 + threadIdx.x) * 4;
  const float* src;
  unsigned short* dst;
  if (e < na) { src = a + e; dst = ao + e; }
  else if (e < na + nb) { src = bsrc + (e - na); dst = bo + (e - na); }
  else if (e < na + nb + nc) { src = csrc + (e - na - nb); dst = co + (e - na - nb); }
  else return;
  f32x4 v = *(const f32x4*)src;
  u16x4 o;
  o.x = f2bf(v.x); o.y = f2bf(v.y); o.z = f2bf(v.z); o.w = f2bf(v.w);
  *(u16x4*)dst = o;
}

// ---------------- 64x64 head-tile transpose: src[b][s][stride] -> dst[bh][d][2048] ----
__global__ __launch_bounds__(256) void transp64(const unsigned short* __restrict__ src,
                                                int stride, int off,
                                                unsigned short* __restrict__ dst) {
  __shared__ __align__(16) unsigned short t[64 * 64];
  const int tid = threadIdx.x;
  const int tt = blockIdx.x, bh = blockIdx.y;
  const int b = bh / 12, h = bh % 12;
  const unsigned short* sbase = src + (size_t)(b * 2048 + tt * 64) * stride + h * 64 + off;
  for (int it = 0; it < 2; ++it) {
    int slot = it * 256 + tid, s = slot >> 3, j = slot & 7;
    short8 v = *(const short8*)(sbase + (size_t)s * stride + j * 8);
    int phys = (s + 8 * j) & 63;
    for (int e = 0; e < 8; ++e)
      t[(j * 8 + e) * 64 + phys] = ((unsigned short*)&v)[e];
  }
  __syncthreads();
  unsigned short* dbase = dst + (size_t)bh * 64 * 2048 + tt * 64;
  for (int it = 0; it < 2; ++it) {
    int slot = it * 256 + tid, d = slot >> 3, c = slot & 7;
    int pc = (c + (d >> 3)) & 7;
    short8 v = *(const short8*)(t + d * 64 + pc * 8);
    *(short8*)(dbase + (size_t)d * 2048 + c * 8) = v;
  }
}

// ---------------- GEMM: C[M][N] = A[M][K] * B[N][K]^T + bias, XCD-swizzled ----------
template <bool OUT_BF16>
__global__ __launch_bounds__(256) void gemm_nt(const unsigned short* __restrict__ A,
                                               const unsigned short* __restrict__ Bm,
                                               const float* __restrict__ bias,
                                               void* __restrict__ Cout,
                                               int M, int N, int K) {
  __shared__ __align__(16) char smem[32768];
  char* As = smem;
  char* Bs = smem + 16384;
  const int tid = threadIdx.x;
  const int w = tid >> 6, l = tid & 63;
  const int wm = w >> 1, wn = w & 1;
  const int gx = gridDim.x;
  const int lin = blockIdx.y * gx + blockIdx.x;
  const int cpx = (gx * gridDim.y) >> 3;
  const int swz = (lin & 7) * cpx + (lin >> 3);
  const int Row0 = (swz / gx) * 128, Col0 = (swz % gx) * 128;

  f32x4 z; z.x = 0.f; z.y = 0.f; z.z = 0.f; z.w = 0.f;
  f32x4 acc[4][4];
  for (int m = 0; m < 4; ++m)
    for (int n = 0; n < 4; ++n) acc[m][n] = z;

  for (int k0 = 0; k0 < K; k0 += 64) {
    for (int it = 0; it < 4; ++it) {
      int slot = it * 256 + tid;
      int row = slot >> 3, j = slot & 7;
      int gc = j ^ (row & 7);
      GLOAD16(A + (size_t)(Row0 + row) * K + k0 + gc * 8, As + slot * 16);
      GLOAD16(Bm + (size_t)(Col0 + row) * K + k0 + gc * 8, Bs + slot * 16);
    }
    __syncthreads();
    for (int kc = 0; kc < 2; ++kc) {
      int c = (l >> 4) + 4 * kc;
      short8 af[4], bf[4];
      for (int m = 0; m < 4; ++m) {
        int t = wm * 64 + m * 16 + (l & 15);
        af[m] = *(const short8*)(As + t * 128 + ((c ^ (t & 7)) * 16));
      }
      for (int n = 0; n < 4; ++n) {
        int t = wn * 64 + n * 16 + (l & 15);
        bf[n] = *(const short8*)(Bs + t * 128 + ((c ^ (t & 7)) * 16));
      }
      for (int m = 0; m < 4; ++m)
        for (int n = 0; n < 4; ++n)
          acc[m][n] = MFMA16(af[m], bf[n], acc[m][n], 0, 0, 0);
    }
    __syncthreads();
  }
  for (int n = 0; n < 4; ++n) {
    int col = Col0 + wn * 64 + n * 16 + (l & 15);
    float bv = bias[col];
    for (int m = 0; m < 4; ++m) {
      int rbase = Row0 + wm * 64 + m * 16 + (l >> 4) * 4;
      for (int r = 0; r < 4; ++r) {
        float v = acc[m][n][r] + bv;
        size_t idx = (size_t)(rbase + r) * N + col;
        if (OUT_BF16) ((unsigned short*)Cout)[idx] = f2bf(v);
        else          ((float*)Cout)[idx] = v;
      }
    }
  }
}

// ---------------- pass1: 4 waves (2 mat x 2 s-half), T=64/wave, s-tile 32, dbuf ------
// 768 1-D blocks, XCD-locality decode (same bh-group -> same XCD). Writes u^T.
__global__ __launch_bounds__(256) void pass1(const unsigned short* __restrict__ qkv,
                                             const unsigned short* __restrict__ vt,
                                             unsigned short* __restrict__ ut) {
  __shared__ __align__(16) char smem[49152];  // 2 bufs x 2 sh x (K1 4K|K2 4K|V 4K)
  const int tid = threadIdx.x, w = tid >> 6, l = tid & 63;
  const int m = w & 1, sh = w >> 1;
  const int g5 = l >> 5, l31 = l & 31;
  int tt, bh;
  xcd_decode(blockIdx.x, tt, bh);
  const int b = bh / 12, h = bh % 12;

  // Q fragments (B-operand of swapped QK): [tb][kc], t = tt*64 + tb*32 + l31
  short8 qf[2][4];
#pragma unroll
  for (int tb = 0; tb < 2; ++tb) {
    const unsigned short* qrow =
        qkv + (size_t)(b * 2048 + tt * 64 + tb * 32 + l31) * 5376 + h * 64 + m * 2 * 768;
#pragma unroll
    for (int kc = 0; kc < 4; ++kc)
      qf[tb][kc] = *(const short8*)(qrow + kc * 16 + g5 * 8);
  }

  f32x16 z16;
#pragma unroll
  for (int i = 0; i < 16; ++i) z16[i] = 0.f;
  f32x16 tacc[2][2];  // [tb][dn]
  tacc[0][0] = z16; tacc[0][1] = z16; tacc[1][0] = z16; tacc[1][1] = z16;

  // stage both halves' K1,K2,V (s-tile 32): 6 GLOAD16/thread
  auto STAGE = [&](char* buf, int si) {
#pragma unroll
    for (int shs = 0; shs < 2; ++shs) {
      int s0 = shs * 1024 + si * 32;
      char* hb = buf + shs * 12288;
      {
        int row = tid >> 3, pc = tid & 7, gc = pc ^ (row & 7);
        const unsigned short* base =
            qkv + (size_t)(b * 2048 + s0 + row) * 5376 + h * 64 + gc * 8;
        GLOAD16(base + 768, hb + tid * 16);              // K1
        GLOAD16(base + 3 * 768, hb + 4096 + tid * 16);   // K2
      }
      {
        int row = tid >> 2, pc = tid & 3, gc = pc ^ ((row >> 1) & 3);
        GLOAD16(vt + (size_t)(bh * 64 + row) * 2048 + s0 + gc * 8,
                hb + 8192 + tid * 16);                   // V^T [64d][32s]
      }
    }
  };

  STAGE(smem, 0);
  __syncthreads();
  for (int si = 0; si < 32; ++si) {
    const char* cur = smem + (si & 1) * 24576 + sh * 12288;
    if (si < 31) STAGE(smem + ((si + 1) & 1) * 24576, si + 1);
    const char* Ks = cur + m * 4096;
    const char* Vs = cur + 8192;

    short8 kreg[4], vreg[4];
#pragma unroll
    for (int kc = 0; kc < 4; ++kc)
      kreg[kc] = *(const short8*)(Ks + l31 * 128 + (((kc * 2 + g5) ^ (l31 & 7)) * 16));
#pragma unroll
    for (int kc2 = 0; kc2 < 2; ++kc2)
#pragma unroll
      for (int dn = 0; dn < 2; ++dn) {
        int drow = dn * 32 + l31, c = kc2 * 2 + g5;
        vreg[kc2 * 2 + dn] =
            *(const short8*)(Vs + drow * 64 + ((c ^ ((drow >> 1) & 3)) * 16));
      }

#pragma unroll
    for (int tb = 0; tb < 2; ++tb) {
      f32x16 a = z16;
#pragma unroll
      for (int kc = 0; kc < 4; ++kc)
        a = MFMA32(kreg[kc], qf[tb][kc], a, 0, 0, 0);
#pragma unroll
      for (int kc2 = 0; kc2 < 2; ++kc2) {
        short8 pa = pv_frag(&a, kc2);
#pragma unroll
        for (int dn = 0; dn < 2; ++dn)
          tacc[tb][dn] = MFMA32(pa, vreg[kc2 * 2 + dn], tacc[tb][dn], 0, 0, 0);
      }
    }
    __syncthreads();
  }

  // epilogue: combine s-halves (per mat), then u^T = silu(t1)*t2 by mat-0 wave
  float* ex = (float*)smem;
  if (sh == 1) {
#pragma unroll
    for (int tb = 0; tb < 2; ++tb)
#pragma unroll
      for (int dn = 0; dn < 2; ++dn)
#pragma unroll
        for (int qd = 0; qd < 4; ++qd) {
          f32x4 v;
          v.x = tacc[tb][dn][qd * 4 + 0]; v.y = tacc[tb][dn][qd * 4 + 1];
          v.z = tacc[tb][dn][qd * 4 + 2]; v.w = tacc[tb][dn][qd * 4 + 3];
          *(f32x4*)((char*)ex + m * 16384 + ((tb * 2 + dn) * 4 + qd) * 1024 + l * 16) = v;
        }
  }
  __syncthreads();
  if (sh == 0) {
#pragma unroll
    for (int tb = 0; tb < 2; ++tb)
#pragma unroll
      for (int dn = 0; dn < 2; ++dn)
#pragma unroll
        for (int qd = 0; qd < 4; ++qd) {
          f32x4 v = *(const f32x4*)((char*)ex + m * 16384 +
                                    ((tb * 2 + dn) * 4 + qd) * 1024 + l * 16);
          tacc[tb][dn][qd * 4 + 0] += v.x; tacc[tb][dn][qd * 4 + 1] += v.y;
          tacc[tb][dn][qd * 4 + 2] += v.z; tacc[tb][dn][qd * 4 + 3] += v.w;
        }
  }
  __syncthreads();
  if (sh == 0 && m == 1) {
#pragma unroll
    for (int tb = 0; tb < 2; ++tb)
#pragma unroll
      for (int dn = 0; dn < 2; ++dn)
#pragma unroll
        for (int qd = 0; qd < 4; ++qd) {
          f32x4 v;
          v.x = tacc[tb][dn][qd * 4 + 0]; v.y = tacc[tb][dn][qd * 4 + 1];
          v.z = tacc[tb][dn][qd * 4 + 2]; v.w = tacc[tb][dn][qd * 4 + 3];
          *(f32x4*)((char*)ex + ((tb * 2 + dn) * 4 + qd) * 1024 + l * 16) = v;
        }
  }
  __syncthreads();
  if (sh == 0 && m == 0) {
    // compute uu, transpose through 4KB swizzled LDS scratch, write u^T coalesced
    char* sc = smem + 32768;   // [64 d][64 t] bf16, tile-swizzled (4KB)
#pragma unroll
    for (int tb = 0; tb < 2; ++tb)
#pragma unroll
      for (int dn = 0; dn < 2; ++dn)
#pragma unroll
        for (int r = 0; r < 16; ++r) {
          float x2 = ex[((tb * 2 + dn) * 4 + (r >> 2)) * 256 + l * 4 + (r & 3)];
          int crow = (r & 3) + 8 * (r >> 2) + 4 * g5;
          int t = tb * 32 + crow;          // local t 0..63
          int d = dn * 32 + l31;
          float x1 = tacc[tb][dn][r];
          float uu = (x1 / (1.f + expf(-x1))) * x2;
          *(unsigned short*)(sc + d * 128 + (((t >> 3) ^ (d & 7)) * 16) + (t & 7) * 2) =
              f2bf(uu);
        }
    asm volatile("s_waitcnt lgkmcnt(0)" ::: "memory");
#pragma unroll
    for (int rr = 0; rr < 8; ++rr) {
      int drow = rr * 8 + (l >> 3), jc = l & 7;
      short8 v = *(const short8*)(sc + drow * 128 + ((jc ^ (drow & 7)) * 16));
      *(short8*)(ut + (size_t)(bh * 64 + drow) * 2048 + tt * 64 + jc * 8) = v;
    }
  }
}

// ---------------- pass2: 4 waves (4 s-quarters), T=64/wave, s-tile 32, dbuf ---------
// 768 1-D blocks, XCD-locality decode. 2 x 32KB buffers.
__global__ __launch_bounds__(256) void pass2(const unsigned short* __restrict__ qkv,
                                             const unsigned short* __restrict__ ut,
                                             float* __restrict__ ctx,
                                             float* __restrict__ partials) {
  __shared__ __align__(16) char smem[65536];  // 2 bufs x 4 quarters x (K3 4K | U 4K)
  const int tid = threadIdx.x, w = tid >> 6, l = tid & 63;
  const int g5 = l >> 5, l31 = l & 31;
  int tt, bh;
  xcd_decode(blockIdx.x, tt, bh);
  const int b = bh / 12, h = bh % 12;

  short8 qf[2][4];
#pragma unroll
  for (int tb = 0; tb < 2; ++tb) {
    const unsigned short* qrow =
        qkv + (size_t)(b * 2048 + tt * 64 + tb * 32 + l31) * 5376 + h * 64 + 4 * 768;
#pragma unroll
    for (int kc = 0; kc < 4; ++kc)
      qf[tb][kc] = *(const short8*)(qrow + kc * 16 + g5 * 8);
  }

  f32x16 z16;
#pragma unroll
  for (int i = 0; i < 16; ++i) z16[i] = 0.f;
  f32x16 ca[2][2];  // [tb][dn]
  ca[0][0] = z16; ca[0][1] = z16; ca[1][0] = z16; ca[1][1] = z16;

  const unsigned short *kp0, *kp1, *kp2, *kp3, *up0, *up1, *up2, *up3;
  {
    int row = tid >> 3, pc = tid & 7, gc = pc ^ (row & 7);
    kp0 = qkv + (size_t)(b * 2048 + row) * 5376 + h * 64 + 5 * 768 + gc * 8;
    kp1 = kp0 + (size_t)512 * 5376;
    kp2 = kp1 + (size_t)512 * 5376;
    kp3 = kp2 + (size_t)512 * 5376;
    int rowv = tid >> 2, pcv = tid & 3, gcv = pcv ^ ((rowv >> 1) & 3);
    up0 = ut + (size_t)(bh * 64 + rowv) * 2048 + gcv * 8;
    up1 = up0 + 512; up2 = up1 + 512; up3 = up2 + 512;
  }
  auto STAGE = [&](char* buf) {
    GLOAD16(kp0, buf + tid * 16);
    GLOAD16(up0, buf + 4096 + tid * 16);
    GLOAD16(kp1, buf + 8192 + tid * 16);
    GLOAD16(up1, buf + 12288 + tid * 16);
    GLOAD16(kp2, buf + 16384 + tid * 16);
    GLOAD16(up2, buf + 20480 + tid * 16);
    GLOAD16(kp3, buf + 24576 + tid * 16);
    GLOAD16(up3, buf + 28672 + tid * 16);
    kp0 += 32 * 5376; kp1 += 32 * 5376; kp2 += 32 * 5376; kp3 += 32 * 5376;
    up0 += 32; up1 += 32; up2 += 32; up3 += 32;
  };

  STAGE(smem);
  __syncthreads();
  for (int si = 0; si < 16; ++si) {
    const char* cur = smem + (si & 1) * 32768;
    if (si < 15) STAGE(smem + ((si + 1) & 1) * 32768);
    const char* Ks = cur + w * 8192;
    const char* Us = Ks + 4096;

    short8 kreg[4], ureg[4];
#pragma unroll
    for (int kc = 0; kc < 4; ++kc)
      kreg[kc] = *(const short8*)(Ks + l31 * 128 + (((kc * 2 + g5) ^ (l31 & 7)) * 16));
#pragma unroll
    for (int kc2 = 0; kc2 < 2; ++kc2)
#pragma unroll
      for (int dn = 0; dn < 2; ++dn) {
        int drow = dn * 32 + l31, c = kc2 * 2 + g5;
        ureg[kc2 * 2 + dn] =
            *(const short8*)(Us + drow * 64 + ((c ^ ((drow >> 1) & 3)) * 16));
      }

#pragma unroll
    for (int tb = 0; tb < 2; ++tb) {
      f32x16 a = z16;
#pragma unroll
      for (int kc = 0; kc < 4; ++kc)
        a = MFMA32(kreg[kc], qf[tb][kc], a, 0, 0, 0);
#pragma unroll
      for (int kc2 = 0; kc2 < 2; ++kc2) {
        short8 pa = pv_frag(&a, kc2);
#pragma unroll
        for (int dn = 0; dn < 2; ++dn)
          ca[tb][dn] = MFMA32(pa, ureg[kc2 * 2 + dn], ca[tb][dn], 0, 0, 0);
      }
    }
    __syncthreads();
  }

  // epilogue: tree-combine quarters -> wave 0
  float* ex = (float*)smem;
  auto DUMP = [&](int region) {
#pragma unroll
    for (int tb = 0; tb < 2; ++tb)
#pragma unroll
      for (int dn = 0; dn < 2; ++dn)
#pragma unroll
        for (int qd = 0; qd < 4; ++qd) {
          f32x4 v;
          v.x = ca[tb][dn][qd * 4 + 0]; v.y = ca[tb][dn][qd * 4 + 1];
          v.z = ca[tb][dn][qd * 4 + 2]; v.w = ca[tb][dn][qd * 4 + 3];
          *(f32x4*)((char*)ex + region * 16384 + ((tb * 2 + dn) * 4 + qd) * 1024 + l * 16) = v;
        }
  };
  auto ACCUM = [&](int region) {
#pragma unroll
    for (int tb = 0; tb < 2; ++tb)
#pragma unroll
      for (int dn = 0; dn < 2; ++dn)
#pragma unroll
        for (int qd = 0; qd < 4; ++qd) {
          f32x4 v = *(const f32x4*)((char*)ex + region * 16384 +
                                    ((tb * 2 + dn) * 4 + qd) * 1024 + l * 16);
          ca[tb][dn][qd * 4 + 0] += v.x; ca[tb][dn][qd * 4 + 1] += v.y;
          ca[tb][dn][qd * 4 + 2] += v.z; ca[tb][dn][qd * 4 + 3] += v.w;
        }
  };
  if (w == 1) DUMP(0);
  if (w == 3) DUMP(1);
  __syncthreads();
  if (w == 0) ACCUM(0);
  if (w == 2) ACCUM(1);
  __syncthreads();
  if (w == 2) DUMP(0);
  __syncthreads();
  float psum = 0.f, psum2 = 0.f;
  if (w == 0) {
    ACCUM(0);
#pragma unroll
    for (int tb = 0; tb < 2; ++tb)
#pragma unroll
      for (int dn = 0; dn < 2; ++dn)
#pragma unroll
        for (int r = 0; r < 16; ++r) {
          int t = tt * 64 + tb * 32 + (r & 3) + 8 * (r >> 2) + 4 * g5;
          int d = dn * 32 + l31;
          float v = ca[tb][dn][r];
          ctx[(size_t)(b * 2048 + t) * 768 + h * 64 + d] = v;
          psum += v; psum2 += v * v;
        }
    for (int off = 32; off > 0; off >>= 1) {
      psum += __shfl_down(psum, off, 64);
      psum2 += __shfl_down(psum2, off, 64);
    }
    if (l == 0) {
      partials[(bh * 32 + tt) * 2] = psum;
      partials[(bh * 32 + tt) * 2 + 1] = psum2;
    }
  }
}

// ---------------- finalize GN stats from 32 partials per group ----------------
__global__ __launch_bounds__(64) void gn_finalize(const float* __restrict__ partials,
                                                  float* __restrict__ stats) {
  const int g = blockIdx.x;
  const int l = threadIdx.x;
  double s = 0.0, s2 = 0.0;
  if (l < 32) {
    s = (double)partials[(g * 32 + l) * 2];
    s2 = (double)partials[(g * 32 + l) * 2 + 1];
  }
  for (int off = 32; off > 0; off >>= 1) {
    s += __shfl_down(s, off, 64);
    s2 += __shfl_down(s2, off, 64);
  }
  if (l == 0) {
    const double N = 2048.0 * 64.0;
    double mean = s / N;
    double var = s2 / N - mean * mean;
    stats[g * 2] = (float)mean;
    stats[g * 2 + 1] = (float)(1.0 / sqrt(var + 1e-5));
  }
}

// ---------------- normalize + affine -> bf16 ----------------
__global__ __launch_bounds__(256) void gn_apply(const float* __restrict__ ctx,
                                                const float* __restrict__ stats,
                                                const float* __restrict__ gw,
                                                const float* __restrict__ gb,
                                                unsigned short* __restrict__ outc) {
  int i = blockIdx.x * 256 + threadIdx.x;
  if (i >= 4096 * 768) return;
  int c = i % 768;
  int b = i / (2048 * 768);
  int g = b * 12 + (c >> 6);
  float v = (ctx[i] - stats[2 * g]) * stats[2 * g + 1];
  outc[i] = f2bf(v * gw[c] + gb[c]);
}

extern "C" void kernel_launch(void* const* d_in, const int* in_sizes, int n_in,
                              void* d_out, int out_size, void* d_ws, size_t ws_size,
                              hipStream_t stream) {
  const float* x   = (const float*)d_in[0];
  const float* Wpw = (const float*)d_in[1];
  const float* Wpb = (const float*)d_in[2];
  const float* gnw = (const float*)d_in[3];
  const float* gnb = (const float*)d_in[4];
  const float* ow  = (const float*)d_in[5];
  const float* ob  = (const float*)d_in[6];
  float* out = (float*)d_out;

  char* ws = (char*)d_ws;
  size_t off = 0;
  auto carve = [&](size_t bytes) {
    char* p = ws + off;
    off = (off + bytes + 255) & ~(size_t)255;
    return p;
  };
  unsigned short* xb   = (unsigned short*)carve((size_t)4096 * 768 * 2);   // x bf16; reused as ctxn
  unsigned short* wb   = (unsigned short*)carve((size_t)5376 * 768 * 2);
  unsigned short* owb  = (unsigned short*)carve((size_t)768 * 768 * 2);
  unsigned short* qkvb = (unsigned short*)carve((size_t)4096 * 5376 * 2);
  unsigned short* vtb  = (unsigned short*)carve((size_t)24 * 64 * 2048 * 2); // V^T
  unsigned short* utb  = (unsigned short*)carve((size_t)24 * 64 * 2048 * 2); // u^T
  float* ctx           = (float*)carve((size_t)4096 * 768 * 4);
  float* partials      = (float*)carve(24 * 32 * 2 * 4);
  float* stats         = (float*)carve(48 * 4);

  const int na = 4096 * 768, nb = 5376 * 768, nc = 768 * 768;
  cvt_all<<<(na + nb + nc) / 4 / 256, 256, 0, stream>>>(x, xb, na, Wpw, wb, nb, ow, owb, nc);

  gemm_nt<true><<<dim3(42, 32), 256, 0, stream>>>(xb, wb, Wpb, qkvb, 4096, 5376, 768);
  transp64<<<dim3(32, 24), 256, 0, stream>>>(qkvb, 5376, 6 * 768, vtb);   // V -> V^T
  pass1<<<768, 256, 0, stream>>>(qkvb, vtb, utb);                         // writes u^T
  pass2<<<768, 256, 0, stream>>>(qkvb, utb, ctx, partials);
  gn_finalize<<<24, 64, 0, stream>>>(partials, stats);
  gn_apply<<<12288, 256, 0, stream>>>(ctx, stats, gnw, gnb, xb);  // xb reused as ctxn
  gemm_nt<false><<<dim3(6, 32), 256, 0, stream>>>(xb, owb, ob, out, 4096, 768, 768);
}